// Round 1
// baseline (1589.951 us; speedup 1.0000x reference)
//
#include <hip/hip_runtime.h>

#define SEQ 2048
#define DIM 128
#define NBH 32
#define NROWS (NBH*SEQ)      // 65536
#define NBLK (NROWS/32)      // 2048
#define SCALE 0.08838834764831845f  // 1/sqrt(128)

// ---------------- LSH hash: PERM[code] == code ^ (code>>1) (binary-reflected Gray code)
__global__ void hash_kernel(const float* __restrict__ qg, const float* __restrict__ kg,
                            const float* __restrict__ proj,
                            int* __restrict__ qh, int* __restrict__ kh)
{
    int gw   = (int)((blockIdx.x * blockDim.x + threadIdx.x) >> 6);
    int lane = threadIdx.x & 63;
    const float* src; int* dst; int row;
    if (gw < NROWS) { src = qg; dst = qh; row = gw; }
    else            { src = kg; dst = kh; row = gw - NROWS; }
    const float* x = src + (size_t)row * DIM;
    float a0=0.f,a1=0.f,a2=0.f,a3=0.f,a4=0.f,a5=0.f,a6=0.f;
    #pragma unroll
    for (int h = 0; h < 2; ++h) {
        int d = lane + 64*h;
        float xv = x[d];
        const float* p = proj + d*7;
        a0 = fmaf(xv, p[0], a0);
        a1 = fmaf(xv, p[1], a1);
        a2 = fmaf(xv, p[2], a2);
        a3 = fmaf(xv, p[3], a3);
        a4 = fmaf(xv, p[4], a4);
        a5 = fmaf(xv, p[5], a5);
        a6 = fmaf(xv, p[6], a6);
    }
    #pragma unroll
    for (int off = 32; off > 0; off >>= 1) {
        a0 += __shfl_xor(a0, off, 64);
        a1 += __shfl_xor(a1, off, 64);
        a2 += __shfl_xor(a2, off, 64);
        a3 += __shfl_xor(a3, off, 64);
        a4 += __shfl_xor(a4, off, 64);
        a5 += __shfl_xor(a5, off, 64);
        a6 += __shfl_xor(a6, off, 64);
    }
    if (lane == 0) {
        int code = 0;
        if (a0 > 0.f) code |= 1;
        if (a1 > 0.f) code |= 2;
        if (a2 > 0.f) code |= 4;
        if (a3 > 0.f) code |= 8;
        if (a4 > 0.f) code |= 16;
        if (a5 > 0.f) code |= 32;
        if (a6 > 0.f) code |= 64;
        dst[row] = code ^ (code >> 1);
    }
}

// ---------------- stable counting sort per (b,h): 128 buckets, bucket-owner threads preserve order
__global__ __launch_bounds__(256) void sort_kernel(const int* __restrict__ qh,
                                                   int* __restrict__ sidx, int* __restrict__ qhs)
{
    __shared__ int h[SEQ];
    __shared__ int startv[128];
    __shared__ int cnt[128];
    const int bh = blockIdx.x;
    const int t  = threadIdx.x;
    for (int i = t; i < SEQ; i += 256) h[i] = qh[bh*SEQ + i];
    if (t < 128) cnt[t] = 0;
    __syncthreads();
    for (int i = t; i < SEQ; i += 256) atomicAdd(&cnt[h[i]], 1);
    __syncthreads();
    if (t == 0) {
        int s = 0;
        for (int v2 = 0; v2 < 128; ++v2) { startv[v2] = s; s += cnt[v2]; }
    }
    __syncthreads();
    if (t < 128) {
        int base = startv[t];
        int c = 0;
        for (int i = 0; i < SEQ; ++i) {
            if (h[i] == t) { sidx[bh*SEQ + base + c] = i; qhs[bh*SEQ + base + c] = t; ++c; }
        }
    }
}

// ---------------- per-32-block criticality -> keep flag
__global__ void crit_kernel(const int* __restrict__ kh, const int* __restrict__ qhs,
                            float* __restrict__ keepg)
{
    int nb = blockIdx.x * blockDim.x + threadIdx.x;
    if (nb >= NBLK) return;
    int c = 0;
    #pragma unroll
    for (int i = 0; i < 32; ++i) c += (kh[nb*32+i] == qhs[nb*32+i]) ? 1 : 0;
    keepg[nb] = (c == 0) ? 1.0f : 0.0f;
}

// ---------------- dense flash attention (fp32, vector ALU), 64 q-rows x 32 k-tile per block
__global__ __launch_bounds__(256, 2) void dense_attn(
    const float* __restrict__ qg, const float* __restrict__ kg,
    const float* __restrict__ vg, float* __restrict__ outg)
{
    __shared__ float Qs[64][132];   // stride 132: 16B-aligned rows, <=2-way bank aliasing
    __shared__ float Ks[32][132];
    __shared__ float Vs[32][132];
    __shared__ float Sc[64][33];
    __shared__ float mrow[64], lrow[64], arow[64];

    const int t  = threadIdx.x;
    const int bh = blockIdx.y;
    const int q0 = blockIdx.x * 64;
    const float* Qg = qg + ((size_t)bh*SEQ + q0) * DIM;
    const float* Kg = kg + (size_t)bh*SEQ*DIM;
    const float* Vg = vg + (size_t)bh*SEQ*DIM;

    for (int i = t; i < 64*32; i += 256) {
        int row = i >> 5, c4 = (i & 31) * 4;
        *(float4*)&Qs[row][c4] = *(const float4*)(Qg + row*DIM + c4);
    }
    if (t < 64) { mrow[t] = -1e30f; lrow[t] = 0.f; }

    const int ty = t >> 4, tx = t & 15;
    const int qi = ty * 4;
    float acc[4][8];
    #pragma unroll
    for (int i = 0; i < 4; ++i)
        #pragma unroll
        for (int j = 0; j < 8; ++j) acc[i][j] = 0.f;

    for (int kt = 0; kt < SEQ/32; ++kt) {
        const float* Kt = Kg + (size_t)kt*32*DIM;
        const float* Vt = Vg + (size_t)kt*32*DIM;
        for (int i = t; i < 32*32; i += 256) {
            int row = i >> 5, c4 = (i & 31) * 4;
            *(float4*)&Ks[row][c4] = *(const float4*)(Kt + row*DIM + c4);
            *(float4*)&Vs[row][c4] = *(const float4*)(Vt + row*DIM + c4);
        }
        __syncthreads();

        float s0[4], s1[4];
        #pragma unroll
        for (int i = 0; i < 4; ++i) { s0[i] = 0.f; s1[i] = 0.f; }
        for (int d = 0; d < DIM; d += 4) {
            float4 b0 = *(const float4*)&Ks[tx][d];
            float4 b1 = *(const float4*)&Ks[tx+16][d];
            #pragma unroll
            for (int i = 0; i < 4; ++i) {
                float4 a = *(const float4*)&Qs[qi+i][d];
                s0[i] = fmaf(a.x,b0.x,s0[i]);
                s0[i] = fmaf(a.y,b0.y,s0[i]);
                s0[i] = fmaf(a.z,b0.z,s0[i]);
                s0[i] = fmaf(a.w,b0.w,s0[i]);
                s1[i] = fmaf(a.x,b1.x,s1[i]);
                s1[i] = fmaf(a.y,b1.y,s1[i]);
                s1[i] = fmaf(a.z,b1.z,s1[i]);
                s1[i] = fmaf(a.w,b1.w,s1[i]);
            }
        }
        #pragma unroll
        for (int i = 0; i < 4; ++i) {
            Sc[qi+i][tx]    = s0[i]*SCALE;
            Sc[qi+i][tx+16] = s1[i]*SCALE;
        }
        __syncthreads();

        if (t < 64) {   // online softmax row update (wave 0)
            float m0 = mrow[t];
            float mx = m0;
            for (int j = 0; j < 32; ++j) mx = fmaxf(mx, Sc[t][j]);
            float alpha = __expf(m0 - mx);
            float ls = 0.f;
            for (int j = 0; j < 32; ++j) {
                float p = __expf(Sc[t][j] - mx);
                Sc[t][j] = p;
                ls += p;
            }
            mrow[t] = mx; arow[t] = alpha;
            lrow[t] = lrow[t]*alpha + ls;
        }
        __syncthreads();

        #pragma unroll
        for (int i = 0; i < 4; ++i) {
            float al = arow[qi+i];
            #pragma unroll
            for (int j = 0; j < 8; ++j) acc[i][j] *= al;
        }
        for (int kk = 0; kk < 32; ++kk) {
            float4 v0 = *(const float4*)&Vs[kk][tx*4];
            float4 v1 = *(const float4*)&Vs[kk][64 + tx*4];
            #pragma unroll
            for (int i = 0; i < 4; ++i) {
                float p = Sc[qi+i][kk];
                acc[i][0]=fmaf(p,v0.x,acc[i][0]);
                acc[i][1]=fmaf(p,v0.y,acc[i][1]);
                acc[i][2]=fmaf(p,v0.z,acc[i][2]);
                acc[i][3]=fmaf(p,v0.w,acc[i][3]);
                acc[i][4]=fmaf(p,v1.x,acc[i][4]);
                acc[i][5]=fmaf(p,v1.y,acc[i][5]);
                acc[i][6]=fmaf(p,v1.z,acc[i][6]);
                acc[i][7]=fmaf(p,v1.w,acc[i][7]);
            }
        }
        __syncthreads();
    }

    #pragma unroll
    for (int i = 0; i < 4; ++i) {
        float inv = 1.f / lrow[qi+i];
        float* orow = outg + ((size_t)bh*SEQ + q0 + qi + i)*DIM;
        float4 o;
        o.x=acc[i][0]*inv; o.y=acc[i][1]*inv; o.z=acc[i][2]*inv; o.w=acc[i][3]*inv;
        *(float4*)(orow + tx*4) = o;
        o.x=acc[i][4]*inv; o.y=acc[i][5]*inv; o.z=acc[i][6]*inv; o.w=acc[i][7]*inv;
        *(float4*)(orow + 64 + tx*4) = o;
    }
}

// ---------------- blocked critical attention + MSE loss accumulation
__global__ __launch_bounds__(256) void crit_attn(
    const float* __restrict__ qg, const float* __restrict__ kg, const float* __restrict__ vg,
    const int* __restrict__ sidx, const float* __restrict__ keepg,
    const float* __restrict__ outg, float* __restrict__ lossp)
{
    __shared__ float Qs[32][132];
    __shared__ float Ks[32][132];
    __shared__ float Vs[32][132];
    __shared__ float Sc[32][33];
    __shared__ float wsum[4];

    const int t  = threadIdx.x;
    const int nb = blockIdx.x;
    const int bh = nb >> 6;             // 64 blocks per head
    const int s0 = (nb & 63) * 32;      // sorted-position / key-row offset within head
    const float kp = keepg[nb];
    const float* Qbase = qg + (size_t)bh*SEQ*DIM;
    const size_t rowbase = (size_t)nb * 32 * DIM;

    for (int i = t; i < 32*32; i += 256) {
        int row = i >> 5, c4 = (i & 31)*4;
        int qsrc = sidx[bh*SEQ + s0 + row];
        *(float4*)&Qs[row][c4] = *(const float4*)(Qbase + (size_t)qsrc*DIM + c4);
        float4 kv = *(const float4*)(kg + rowbase + (size_t)row*DIM + c4);
        kv.x*=kp; kv.y*=kp; kv.z*=kp; kv.w*=kp;
        *(float4*)&Ks[row][c4] = kv;
        *(float4*)&Vs[row][c4] = *(const float4*)(vg + rowbase + (size_t)row*DIM + c4);
    }
    __syncthreads();

    const int r = t >> 3, u = t & 7;
    {
        float s[4] = {0.f,0.f,0.f,0.f};
        for (int d = 0; d < DIM; d += 4) {
            float4 a = *(const float4*)&Qs[r][d];
            #pragma unroll
            for (int j = 0; j < 4; ++j) {
                float4 b = *(const float4*)&Ks[u + 8*j][d];
                s[j]=fmaf(a.x,b.x,s[j]);
                s[j]=fmaf(a.y,b.y,s[j]);
                s[j]=fmaf(a.z,b.z,s[j]);
                s[j]=fmaf(a.w,b.w,s[j]);
            }
        }
        #pragma unroll
        for (int j = 0; j < 4; ++j) Sc[r][u+8*j] = s[j]*SCALE;
    }
    __syncthreads();
    if (t < 32) {   // full softmax of one 32-wide row, normalized in place
        float mx = -1e30f;
        for (int j = 0; j < 32; ++j) mx = fmaxf(mx, Sc[t][j]);
        float ls = 0.f;
        for (int j = 0; j < 32; ++j) { float p = __expf(Sc[t][j]-mx); Sc[t][j] = p; ls += p; }
        float inv = 1.f/ls;
        for (int j = 0; j < 32; ++j) Sc[t][j] *= inv;
    }
    __syncthreads();

    float sq = 0.f;
    {
        float acc[4][4];
        #pragma unroll
        for (int a2 = 0; a2 < 4; ++a2)
            #pragma unroll
            for (int b2 = 0; b2 < 4; ++b2) acc[a2][b2] = 0.f;
        for (int kk = 0; kk < 32; ++kk) {
            float p = Sc[r][kk];
            #pragma unroll
            for (int kq = 0; kq < 4; ++kq) {
                float4 vv = *(const float4*)&Vs[kk][kq*32 + u*4];
                acc[kq][0]=fmaf(p,vv.x,acc[kq][0]);
                acc[kq][1]=fmaf(p,vv.y,acc[kq][1]);
                acc[kq][2]=fmaf(p,vv.z,acc[kq][2]);
                acc[kq][3]=fmaf(p,vv.w,acc[kq][3]);
            }
        }
        const float* orow = outg + rowbase + (size_t)r*DIM;
        #pragma unroll
        for (int kq = 0; kq < 4; ++kq) {
            float4 oa = *(const float4*)(orow + kq*32 + u*4);
            float d0=acc[kq][0]-oa.x, d1=acc[kq][1]-oa.y, d2=acc[kq][2]-oa.z, d3=acc[kq][3]-oa.w;
            sq += d0*d0 + d1*d1 + d2*d2 + d3*d3;
        }
    }
    #pragma unroll
    for (int off = 32; off > 0; off >>= 1) sq += __shfl_down(sq, off, 64);
    if ((t & 63) == 0) wsum[t>>6] = sq;
    __syncthreads();
    if (t == 0) atomicAdd(lossp, (wsum[0]+wsum[1]+wsum[2]+wsum[3]) * (1.0f/8388608.0f));
}

extern "C" void kernel_launch(void* const* d_in, const int* in_sizes, int n_in,
                              void* d_out, int out_size, void* d_ws, size_t ws_size,
                              hipStream_t stream)
{
    const float* q    = (const float*)d_in[0];
    const float* k    = (const float*)d_in[1];
    const float* v    = (const float*)d_in[2];
    const float* proj = (const float*)d_in[3];
    float* out   = (float*)d_out;
    float* lossp = out + (out_size - 1);

    int* qh   = (int*)d_ws;
    int* kh   = qh + NROWS;
    int* sidx = kh + NROWS;
    int* qhs  = sidx + NROWS;
    float* keepg = (float*)(qhs + NROWS);

    hipMemsetAsync(lossp, 0, sizeof(float), stream);
    hash_kernel<<<(2*NROWS)/4, 256, 0, stream>>>(q, k, proj, qh, kh);
    sort_kernel<<<NBH, 256, 0, stream>>>(qh, sidx, qhs);
    crit_kernel<<<NBLK/256, 256, 0, stream>>>(kh, qhs, keepg);
    dense_attn<<<dim3(SEQ/64, NBH), 256, 0, stream>>>(q, k, v, out);
    crit_attn<<<NBLK, 256, 0, stream>>>(q, k, v, sidx, keepg, out, lossp);
}

// Round 2
// 509.348 us; speedup vs baseline: 3.1215x; 3.1215x over previous
//
#include <hip/hip_runtime.h>

#define SEQ 2048
#define DIM 128
#define NBH 32
#define NROWS (NBH*SEQ)      // 65536
#define NBLK (NROWS/32)      // 2048
#define SCALE 0.08838834764831845f  // 1/sqrt(128)

typedef __attribute__((ext_vector_type(8))) short short8;
typedef __attribute__((ext_vector_type(16))) float float16;

__device__ __forceinline__ unsigned short f2bf(float x) {
    union { float f; unsigned u; } v; v.f = x;
    unsigned r = v.u + 0x7fffu + ((v.u >> 16) & 1u);   // RNE
    return (unsigned short)(r >> 16);
}

// ---------------- LSH hash: PERM[code] == code ^ (code>>1) (binary-reflected Gray code)
__global__ void hash_kernel(const float* __restrict__ qg, const float* __restrict__ kg,
                            const float* __restrict__ proj,
                            int* __restrict__ qh, int* __restrict__ kh)
{
    int gw   = (int)((blockIdx.x * blockDim.x + threadIdx.x) >> 6);
    int lane = threadIdx.x & 63;
    const float* src; int* dst; int row;
    if (gw < NROWS) { src = qg; dst = qh; row = gw; }
    else            { src = kg; dst = kh; row = gw - NROWS; }
    const float* x = src + (size_t)row * DIM;
    float a0=0.f,a1=0.f,a2=0.f,a3=0.f,a4=0.f,a5=0.f,a6=0.f;
    #pragma unroll
    for (int h = 0; h < 2; ++h) {
        int d = lane + 64*h;
        float xv = x[d];
        const float* p = proj + d*7;
        a0 = fmaf(xv, p[0], a0);
        a1 = fmaf(xv, p[1], a1);
        a2 = fmaf(xv, p[2], a2);
        a3 = fmaf(xv, p[3], a3);
        a4 = fmaf(xv, p[4], a4);
        a5 = fmaf(xv, p[5], a5);
        a6 = fmaf(xv, p[6], a6);
    }
    #pragma unroll
    for (int off = 32; off > 0; off >>= 1) {
        a0 += __shfl_xor(a0, off, 64);
        a1 += __shfl_xor(a1, off, 64);
        a2 += __shfl_xor(a2, off, 64);
        a3 += __shfl_xor(a3, off, 64);
        a4 += __shfl_xor(a4, off, 64);
        a5 += __shfl_xor(a5, off, 64);
        a6 += __shfl_xor(a6, off, 64);
    }
    if (lane == 0) {
        int code = 0;
        if (a0 > 0.f) code |= 1;
        if (a1 > 0.f) code |= 2;
        if (a2 > 0.f) code |= 4;
        if (a3 > 0.f) code |= 8;
        if (a4 > 0.f) code |= 16;
        if (a5 > 0.f) code |= 32;
        if (a6 > 0.f) code |= 64;
        dst[row] = code ^ (code >> 1);
    }
}

// ---------------- stable counting sort per (b,h): 128 buckets, bucket-owner threads preserve order
__global__ __launch_bounds__(256) void sort_kernel(const int* __restrict__ qh,
                                                   int* __restrict__ sidx, int* __restrict__ qhs)
{
    __shared__ int h[SEQ];
    __shared__ int startv[128];
    __shared__ int cnt[128];
    const int bh = blockIdx.x;
    const int t  = threadIdx.x;
    for (int i = t; i < SEQ; i += 256) h[i] = qh[bh*SEQ + i];
    if (t < 128) cnt[t] = 0;
    __syncthreads();
    for (int i = t; i < SEQ; i += 256) atomicAdd(&cnt[h[i]], 1);
    __syncthreads();
    if (t == 0) {
        int s = 0;
        for (int v2 = 0; v2 < 128; ++v2) { startv[v2] = s; s += cnt[v2]; }
    }
    __syncthreads();
    if (t < 128) {
        int base = startv[t];
        int c = 0;
        for (int i = 0; i < SEQ; ++i) {
            if (h[i] == t) { sidx[bh*SEQ + base + c] = i; qhs[bh*SEQ + base + c] = t; ++c; }
        }
    }
}

// ---------------- per-32-block criticality -> keep flag
__global__ void crit_kernel(const int* __restrict__ kh, const int* __restrict__ qhs,
                            float* __restrict__ keepg)
{
    int nb = blockIdx.x * blockDim.x + threadIdx.x;
    if (nb >= NBLK) return;
    int c = 0;
    #pragma unroll
    for (int i = 0; i < 32; ++i) c += (kh[nb*32+i] == qhs[nb*32+i]) ? 1 : 0;
    keepg[nb] = (c == 0) ? 1.0f : 0.0f;
}

// ---------------- dense flash attention, bf16 MFMA (32x32x16), 128 q-rows/block, 32-key tiles
// Wave w owns q rows [w*32, w*32+32). S^T = K·Q^T so softmax state is per-lane (q = lane&31).
// O^T accumulated in 64 VGPRs; P^T routed through wave-private LDS into B-operand layout.
__global__ __launch_bounds__(256, 2) void dense_attn_mfma(
    const float* __restrict__ qg, const float* __restrict__ kg,
    const float* __restrict__ vg, float* __restrict__ outg)
{
    __shared__ __align__(16) unsigned short Ks[32][136];     // [key][d], stride 272B: b128 reads 2-way free
    __shared__ __align__(16) unsigned short Vt[128][40];     // [d][key] transposed, stride 80B
    __shared__ __align__(16) unsigned short Pq[4][32][40];   // per-wave P [q][key], stride 80B

    const int t    = threadIdx.x;
    const int lane = t & 63;
    const int w    = t >> 6;
    const int q5   = lane >> 5;
    const int l31  = lane & 31;

    // XCD swizzle: b&7 -> XCD; 16 q-blocks of one head co-resident on one XCD (K+V 2MB fits 4MB L2)
    const int b    = blockIdx.x;
    const int slot = b >> 3;
    const int head = (b & 7) * 4 + (slot >> 4);
    const int qblk = slot & 15;

    const float* Qg = qg + ((size_t)head*SEQ + qblk*128 + w*32) * DIM;
    const float* Kg = kg + (size_t)head*SEQ*DIM;
    const float* Vg = vg + (size_t)head*SEQ*DIM;

    // Q fragments (B-operand, registers for the whole block): lane holds q=l31, d=ch*16+q5*8+j
    short8 Qf[8];
    #pragma unroll
    for (int ch = 0; ch < 8; ++ch) {
        const float* p = Qg + (size_t)l31*DIM + ch*16 + q5*8;
        float4 f0 = *(const float4*)p;
        float4 f1 = *(const float4*)(p + 4);
        short8 qv;
        qv[0]=(short)f2bf(f0.x); qv[1]=(short)f2bf(f0.y); qv[2]=(short)f2bf(f0.z); qv[3]=(short)f2bf(f0.w);
        qv[4]=(short)f2bf(f1.x); qv[5]=(short)f2bf(f1.y); qv[6]=(short)f2bf(f1.z); qv[7]=(short)f2bf(f1.w);
        Qf[ch] = qv;
    }

    float16 o[4];
    #pragma unroll
    for (int mt = 0; mt < 4; ++mt)
        #pragma unroll
        for (int r = 0; r < 16; ++r) o[mt][r] = 0.f;
    float m_run = -1e30f, l_run = 0.f;

    for (int kt = 0; kt < SEQ/32; ++kt) {
        __syncthreads();   // previous iteration's frag reads done before overwrite
        {   // stage K tile -> bf16 LDS (row-major)
            const int r = t >> 3, c = t & 7;
            const float* p = Kg + (size_t)kt*32*DIM + (size_t)r*DIM + c*16;
            float4 a0 = *(const float4*)p,     a1 = *(const float4*)(p+4);
            float4 a2 = *(const float4*)(p+8), a3 = *(const float4*)(p+12);
            short8 x0, x1;
            x0[0]=(short)f2bf(a0.x); x0[1]=(short)f2bf(a0.y); x0[2]=(short)f2bf(a0.z); x0[3]=(short)f2bf(a0.w);
            x0[4]=(short)f2bf(a1.x); x0[5]=(short)f2bf(a1.y); x0[6]=(short)f2bf(a1.z); x0[7]=(short)f2bf(a1.w);
            x1[0]=(short)f2bf(a2.x); x1[1]=(short)f2bf(a2.y); x1[2]=(short)f2bf(a2.z); x1[3]=(short)f2bf(a2.w);
            x1[4]=(short)f2bf(a3.x); x1[5]=(short)f2bf(a3.y); x1[6]=(short)f2bf(a3.z); x1[7]=(short)f2bf(a3.w);
            *(short8*)&Ks[r][c*16]     = x0;
            *(short8*)&Ks[r][c*16 + 8] = x1;
        }
        {   // stage V tile transposed -> Vt[d][key], packed row-pair b32 writes
            const int rp = t & 15, c = t >> 4;
            const float* p0 = Vg + (size_t)kt*32*DIM + (size_t)(2*rp)*DIM + c*8;
            const float* p1 = p0 + DIM;
            float4 a0 = *(const float4*)p0, a1 = *(const float4*)(p0+4);
            float4 b0 = *(const float4*)p1, b1 = *(const float4*)(p1+4);
            float va[8] = {a0.x,a0.y,a0.z,a0.w,a1.x,a1.y,a1.z,a1.w};
            float vb[8] = {b0.x,b0.y,b0.z,b0.w,b1.x,b1.y,b1.z,b1.w};
            #pragma unroll
            for (int i = 0; i < 8; ++i) {
                unsigned pkd = (unsigned)f2bf(va[i]) | ((unsigned)f2bf(vb[i]) << 16);
                *(unsigned*)&Vt[c*8 + i][2*rp] = pkd;
            }
        }
        __syncthreads();

        // S^T = K·Q^T : A[m=key][k=d] from Ks, B[k=d][n=q] = Qf
        float16 s;
        #pragma unroll
        for (int r = 0; r < 16; ++r) s[r] = 0.f;
        #pragma unroll
        for (int ch = 0; ch < 8; ++ch) {
            short8 kf = *(const short8*)&Ks[l31][ch*16 + q5*8];
            s = __builtin_amdgcn_mfma_f32_32x32x16_bf16(kf, Qf[ch], s, 0, 0, 0);
        }

        // online softmax: lane's keys = (reg&3)+8*(reg>>2)+4*q5; other half on lane^32
        float mloc = -1e30f;
        #pragma unroll
        for (int r = 0; r < 16; ++r) { s[r] *= SCALE; mloc = fmaxf(mloc, s[r]); }
        mloc = fmaxf(mloc, __shfl_xor(mloc, 32, 64));
        const float mnew  = fmaxf(m_run, mloc);
        const float alpha = __expf(m_run - mnew);
        float lloc = 0.f;
        unsigned pk[8];
        #pragma unroll
        for (int rp = 0; rp < 8; ++rp) {
            float p0 = __expf(s[2*rp]   - mnew);
            float p1 = __expf(s[2*rp+1] - mnew);
            lloc += p0 + p1;
            pk[rp] = (unsigned)f2bf(p0) | ((unsigned)f2bf(p1) << 16);
        }
        lloc += __shfl_xor(lloc, 32, 64);
        l_run = l_run * alpha + lloc;
        const bool need = mloc > m_run;
        m_run = mnew;
        if (__ballot(need)) {   // wave-uniform skip when no row max moved
            #pragma unroll
            for (int mt = 0; mt < 4; ++mt)
                #pragma unroll
                for (int r = 0; r < 16; ++r) o[mt][r] *= alpha;
        }

        // P^T -> wave-private LDS [q][key] (reg pair = consecutive keys)
        #pragma unroll
        for (int rp = 0; rp < 8; ++rp) {
            const int key = 2*(rp & 1) + 8*(rp >> 1) + 4*q5;
            *(unsigned*)&Pq[w][l31][key] = pk[rp];
        }

        // O^T += V^T·P^T : A[m=d][k=key] from Vt, B[k=key][n=q] from Pq
        #pragma unroll
        for (int c = 0; c < 2; ++c) {
            short8 pf = *(const short8*)&Pq[w][l31][c*16 + q5*8];
            #pragma unroll
            for (int mt = 0; mt < 4; ++mt) {
                short8 vf = *(const short8*)&Vt[mt*32 + l31][c*16 + q5*8];
                o[mt] = __builtin_amdgcn_mfma_f32_32x32x16_bf16(vf, pf, o[mt], 0, 0, 0);
            }
        }
    }

    // epilogue: O^T C-layout col=q=l31, row=(reg&3)+8*(reg>>2)+4*q5 (+32*mt) -> float4 stores
    const float inv = 1.f / l_run;
    float* orow = outg + ((size_t)head*SEQ + qblk*128 + w*32 + l31) * DIM;
    #pragma unroll
    for (int mt = 0; mt < 4; ++mt)
        #pragma unroll
        for (int rg = 0; rg < 4; ++rg) {
            const int d0 = mt*32 + rg*8 + q5*4;
            float4 ov;
            ov.x = o[mt][rg*4+0]*inv; ov.y = o[mt][rg*4+1]*inv;
            ov.z = o[mt][rg*4+2]*inv; ov.w = o[mt][rg*4+3]*inv;
            *(float4*)(orow + d0) = ov;
        }
}

// ---------------- blocked critical attention + MSE loss accumulation
__global__ __launch_bounds__(256) void crit_attn(
    const float* __restrict__ qg, const float* __restrict__ kg, const float* __restrict__ vg,
    const int* __restrict__ sidx, const float* __restrict__ keepg,
    const float* __restrict__ outg, float* __restrict__ lossp)
{
    __shared__ float Qs[32][132];
    __shared__ float Ks2[32][132];
    __shared__ float Vs[32][132];
    __shared__ float Sc[32][33];
    __shared__ float wsum[4];

    const int t  = threadIdx.x;
    const int nb = blockIdx.x;
    const int bh = nb >> 6;             // 64 blocks per head
    const int s0 = (nb & 63) * 32;      // sorted-position / key-row offset within head
    const float kp = keepg[nb];
    const float* Qbase = qg + (size_t)bh*SEQ*DIM;
    const size_t rowbase = (size_t)nb * 32 * DIM;

    for (int i = t; i < 32*32; i += 256) {
        int row = i >> 5, c4 = (i & 31)*4;
        int qsrc = sidx[bh*SEQ + s0 + row];
        *(float4*)&Qs[row][c4] = *(const float4*)(Qbase + (size_t)qsrc*DIM + c4);
        float4 kv = *(const float4*)(kg + rowbase + (size_t)row*DIM + c4);
        kv.x*=kp; kv.y*=kp; kv.z*=kp; kv.w*=kp;
        *(float4*)&Ks2[row][c4] = kv;
        *(float4*)&Vs[row][c4] = *(const float4*)(vg + rowbase + (size_t)row*DIM + c4);
    }
    __syncthreads();

    const int r = t >> 3, u = t & 7;
    {
        float s[4] = {0.f,0.f,0.f,0.f};
        for (int d = 0; d < DIM; d += 4) {
            float4 a = *(const float4*)&Qs[r][d];
            #pragma unroll
            for (int j = 0; j < 4; ++j) {
                float4 bb = *(const float4*)&Ks2[u + 8*j][d];
                s[j]=fmaf(a.x,bb.x,s[j]);
                s[j]=fmaf(a.y,bb.y,s[j]);
                s[j]=fmaf(a.z,bb.z,s[j]);
                s[j]=fmaf(a.w,bb.w,s[j]);
            }
        }
        #pragma unroll
        for (int j = 0; j < 4; ++j) Sc[r][u+8*j] = s[j]*SCALE;
    }
    __syncthreads();
    if (t < 32) {
        float mx = -1e30f;
        for (int j = 0; j < 32; ++j) mx = fmaxf(mx, Sc[t][j]);
        float ls = 0.f;
        for (int j = 0; j < 32; ++j) { float p = __expf(Sc[t][j]-mx); Sc[t][j] = p; ls += p; }
        float inv = 1.f/ls;
        for (int j = 0; j < 32; ++j) Sc[t][j] *= inv;
    }
    __syncthreads();

    float sq = 0.f;
    {
        float acc[4][4];
        #pragma unroll
        for (int a2 = 0; a2 < 4; ++a2)
            #pragma unroll
            for (int b2 = 0; b2 < 4; ++b2) acc[a2][b2] = 0.f;
        for (int kk = 0; kk < 32; ++kk) {
            float p = Sc[r][kk];
            #pragma unroll
            for (int kq = 0; kq < 4; ++kq) {
                float4 vv = *(const float4*)&Vs[kk][kq*32 + u*4];
                acc[kq][0]=fmaf(p,vv.x,acc[kq][0]);
                acc[kq][1]=fmaf(p,vv.y,acc[kq][1]);
                acc[kq][2]=fmaf(p,vv.z,acc[kq][2]);
                acc[kq][3]=fmaf(p,vv.w,acc[kq][3]);
            }
        }
        const float* orow = outg + rowbase + (size_t)r*DIM;
        #pragma unroll
        for (int kq = 0; kq < 4; ++kq) {
            float4 oa = *(const float4*)(orow + kq*32 + u*4);
            float d0=acc[kq][0]-oa.x, d1=acc[kq][1]-oa.y, d2=acc[kq][2]-oa.z, d3=acc[kq][3]-oa.w;
            sq += d0*d0 + d1*d1 + d2*d2 + d3*d3;
        }
    }
    #pragma unroll
    for (int off = 32; off > 0; off >>= 1) sq += __shfl_down(sq, off, 64);
    if ((t & 63) == 0) wsum[t>>6] = sq;
    __syncthreads();
    if (t == 0) atomicAdd(lossp, (wsum[0]+wsum[1]+wsum[2]+wsum[3]) * (1.0f/8388608.0f));
}

extern "C" void kernel_launch(void* const* d_in, const int* in_sizes, int n_in,
                              void* d_out, int out_size, void* d_ws, size_t ws_size,
                              hipStream_t stream)
{
    const float* q    = (const float*)d_in[0];
    const float* k    = (const float*)d_in[1];
    const float* v    = (const float*)d_in[2];
    const float* proj = (const float*)d_in[3];
    float* out   = (float*)d_out;
    float* lossp = out + (out_size - 1);

    int* qh   = (int*)d_ws;
    int* kh   = qh + NROWS;
    int* sidx = kh + NROWS;
    int* qhs  = sidx + NROWS;
    float* keepg = (float*)(qhs + NROWS);

    hipMemsetAsync(lossp, 0, sizeof(float), stream);
    hash_kernel<<<(2*NROWS)/4, 256, 0, stream>>>(q, k, proj, qh, kh);
    sort_kernel<<<NBH, 256, 0, stream>>>(qh, sidx, qhs);
    crit_kernel<<<NBLK/256, 256, 0, stream>>>(kh, qhs, keepg);
    dense_attn_mfma<<<512, 256, 0, stream>>>(q, k, v, out);
    crit_attn<<<NBLK, 256, 0, stream>>>(q, k, v, sidx, keepg, out, lossp);
}

// Round 3
// 471.696 us; speedup vs baseline: 3.3707x; 1.0798x over previous
//
#include <hip/hip_runtime.h>
#include <hip/hip_bf16.h>

#define SEQ 2048
#define DIM 128
#define NBH 32
#define NROWS (NBH*SEQ)      // 65536
#define NBLK (NROWS/32)      // 2048
#define SCALE 0.08838834764831845f  // 1/sqrt(128)
#define QSC (0.08838834764831845f * 1.4426950408889634f)  // SCALE*log2(e): exp2(s') == exp(s*SCALE)

typedef __attribute__((ext_vector_type(8))) short short8;
typedef __attribute__((ext_vector_type(16))) float float16;

__device__ __forceinline__ unsigned short f2bf(float x) {
    union { float f; unsigned u; } v; v.f = x;
    unsigned r = v.u + 0x7fffu + ((v.u >> 16) & 1u);   // RNE
    return (unsigned short)(r >> 16);
}
__device__ __forceinline__ unsigned pack_bf16(float a, float b) {
    float2 f; f.x = a; f.y = b;
    __hip_bfloat162 h = __float22bfloat162_rn(f);
    union { __hip_bfloat162 h2; unsigned u; } cv; cv.h2 = h; return cv.u;
}
__device__ __forceinline__ void gl_lds16(const void* g, void* l) {
    __builtin_amdgcn_global_load_lds((const __attribute__((address_space(1))) unsigned int*)g,
                                     (__attribute__((address_space(3))) unsigned int*)l, 16, 0, 0);
}

// ---------------- LSH hash: PERM[code] == code ^ (code>>1)
__global__ void hash_kernel(const float* __restrict__ qg, const float* __restrict__ kg,
                            const float* __restrict__ proj,
                            int* __restrict__ qh, int* __restrict__ kh)
{
    int gw   = (int)((blockIdx.x * blockDim.x + threadIdx.x) >> 6);
    int lane = threadIdx.x & 63;
    const float* src; int* dst; int row;
    if (gw < NROWS) { src = qg; dst = qh; row = gw; }
    else            { src = kg; dst = kh; row = gw - NROWS; }
    const float* x = src + (size_t)row * DIM;
    float a0=0.f,a1=0.f,a2=0.f,a3=0.f,a4=0.f,a5=0.f,a6=0.f;
    #pragma unroll
    for (int h = 0; h < 2; ++h) {
        int d = lane + 64*h;
        float xv = x[d];
        const float* p = proj + d*7;
        a0 = fmaf(xv, p[0], a0); a1 = fmaf(xv, p[1], a1);
        a2 = fmaf(xv, p[2], a2); a3 = fmaf(xv, p[3], a3);
        a4 = fmaf(xv, p[4], a4); a5 = fmaf(xv, p[5], a5);
        a6 = fmaf(xv, p[6], a6);
    }
    #pragma unroll
    for (int off = 32; off > 0; off >>= 1) {
        a0 += __shfl_xor(a0, off, 64); a1 += __shfl_xor(a1, off, 64);
        a2 += __shfl_xor(a2, off, 64); a3 += __shfl_xor(a3, off, 64);
        a4 += __shfl_xor(a4, off, 64); a5 += __shfl_xor(a5, off, 64);
        a6 += __shfl_xor(a6, off, 64);
    }
    if (lane == 0) {
        int code = 0;
        if (a0 > 0.f) code |= 1;  if (a1 > 0.f) code |= 2;
        if (a2 > 0.f) code |= 4;  if (a3 > 0.f) code |= 8;
        if (a4 > 0.f) code |= 16; if (a5 > 0.f) code |= 32;
        if (a6 > 0.f) code |= 64;
        dst[row] = code ^ (code >> 1);
    }
}

// ---------------- stable counting sort per (b,h)
__global__ __launch_bounds__(256) void sort_kernel(const int* __restrict__ qh,
                                                   int* __restrict__ sidx, int* __restrict__ qhs)
{
    __shared__ int h[SEQ];
    __shared__ int startv[128];
    __shared__ int cnt[128];
    const int bh = blockIdx.x;
    const int t  = threadIdx.x;
    for (int i = t; i < SEQ; i += 256) h[i] = qh[bh*SEQ + i];
    if (t < 128) cnt[t] = 0;
    __syncthreads();
    for (int i = t; i < SEQ; i += 256) atomicAdd(&cnt[h[i]], 1);
    __syncthreads();
    if (t == 0) {
        int s = 0;
        for (int v2 = 0; v2 < 128; ++v2) { startv[v2] = s; s += cnt[v2]; }
    }
    __syncthreads();
    if (t < 128) {
        int base = startv[t];
        int c = 0;
        for (int i = 0; i < SEQ; ++i) {
            if (h[i] == t) { sidx[bh*SEQ + base + c] = i; qhs[bh*SEQ + base + c] = t; ++c; }
        }
    }
}

// ---------------- per-32-block criticality -> keep flag
__global__ void crit_kernel(const int* __restrict__ kh, const int* __restrict__ qhs,
                            float* __restrict__ keepg)
{
    int nb = blockIdx.x * blockDim.x + threadIdx.x;
    if (nb >= NBLK) return;
    int c = 0;
    #pragma unroll
    for (int i = 0; i < 32; ++i) c += (kh[nb*32+i] == qhs[nb*32+i]) ? 1 : 0;
    keepg[nb] = (c == 0) ? 1.0f : 0.0f;
}

// ---------------- prep: K -> bf16 row-major; V -> bf16 transposed [h][d][key]
__global__ __launch_bounds__(256) void prep_kernel(const float* __restrict__ kg,
                                                   const float* __restrict__ vg,
                                                   unsigned short* __restrict__ kbf,
                                                   unsigned short* __restrict__ vtg)
{
    __shared__ unsigned short T[128][72];   // stride 72 shorts (144B): balanced-bank b128 readback
    const int t  = threadIdx.x;
    const int h  = blockIdx.x >> 5;
    const int sl = blockIdx.x & 31;                     // 64-key slab
    const size_t base = ((size_t)h*SEQ + sl*64) * DIM;  // slab start (elements)

    // K: straight elementwise convert (coalesced both ways)
    #pragma unroll
    for (int i = 0; i < 8; ++i) {
        const float4 f = *(const float4*)(kg + base + ((size_t)i*256 + t)*4);
        uint2 pk; pk.x = pack_bf16(f.x, f.y); pk.y = pack_bf16(f.z, f.w);
        *(uint2*)(kbf + base + ((size_t)i*256 + t)*4) = pk;
    }

    // V: transpose 64 keys x 128 d through LDS
    const int kk = t & 63, seg = t >> 6;   // seg: 32-d slice
    #pragma unroll
    for (int i = 0; i < 8; ++i) {
        float4 f = *(const float4*)(vg + base + (size_t)kk*DIM + seg*32 + i*4);
        T[seg*32 + i*4 + 0][kk] = f2bf(f.x);
        T[seg*32 + i*4 + 1][kk] = f2bf(f.y);
        T[seg*32 + i*4 + 2][kk] = f2bf(f.z);
        T[seg*32 + i*4 + 3][kk] = f2bf(f.w);
    }
    __syncthreads();
    const int r = t >> 1, hf = t & 1;
    unsigned short* dst = vtg + ((size_t)h*DIM + r)*SEQ + sl*64 + hf*32;
    #pragma unroll
    for (int i = 0; i < 4; ++i)
        *(short8*)(dst + i*8) = *(const short8*)&T[r][hf*32 + i*8];
}

// ---------------- dense flash attention: bf16 MFMA, max-free softmax, async staging,
// double-buffered 64-key macro-tiles, XOR-swizzled LDS (no padding: global_load_lds dest).
__global__ __launch_bounds__(256, 2) void dense_attn_mfma(
    const unsigned short* __restrict__ kbf, const unsigned short* __restrict__ vtg,
    const float* __restrict__ qg, float* __restrict__ outg)
{
    __shared__ __align__(16) unsigned short Kb[2][64*128];   // [buf][key(64) x d(128)] 16KB each
    __shared__ __align__(16) unsigned short Vb[2][128*64];   // [buf][d(128) x key(64)] 16KB each

    const int t    = threadIdx.x;
    const int lane = t & 63;
    const int w    = t >> 6;
    const int q5   = lane >> 5;
    const int l31  = lane & 31;

    const int b    = blockIdx.x;
    const int slot = b >> 3;
    const int head = (b & 7) * 4 + (slot >> 4);   // XCD swizzle: head group per XCD
    const int qblk = slot & 15;

    const float* Qg = qg + ((size_t)head*SEQ + qblk*128 + w*32) * DIM;
    const unsigned short* Kh = kbf + (size_t)head*SEQ*DIM;
    const unsigned short* Vh = vtg + (size_t)head*DIM*SEQ;

    // Q frags (B-operand), pre-scaled by SCALE*log2e: lane q=l31, d=ch*16+q5*8+j
    union FR { unsigned u[4]; short8 s; };
    short8 Qf[8];
    #pragma unroll
    for (int ch = 0; ch < 8; ++ch) {
        const float* p = Qg + (size_t)l31*DIM + ch*16 + q5*8;
        float4 f0 = *(const float4*)p;
        float4 f1 = *(const float4*)(p + 4);
        FR fr;
        fr.u[0] = pack_bf16(f0.x*QSC, f0.y*QSC);
        fr.u[1] = pack_bf16(f0.z*QSC, f0.w*QSC);
        fr.u[2] = pack_bf16(f1.x*QSC, f1.y*QSC);
        fr.u[3] = pack_bf16(f1.z*QSC, f1.w*QSC);
        Qf[ch] = fr.s;
    }

    float16 o[4];
    #pragma unroll
    for (int mt = 0; mt < 4; ++mt)
        #pragma unroll
        for (int r = 0; r < 16; ++r) o[mt][r] = 0.f;
    float lsum = 0.f;

    // async stage one 64-key macro-tile (K 16KB + V^T 16KB), 8 instrs/wave
    auto stage = [&](int buf, int kt) {
        #pragma unroll
        for (int i = 0; i < 4; ++i) {
            const int j = w*4 + i;
            const int r = j*4 + (lane >> 4);
            const int u = (lane & 15) ^ (r & 7);          // 16B-unit XOR swizzle
            gl_lds16(Kh + ((size_t)(kt*64 + r))*DIM + u*8, &Kb[buf][j*512]);
        }
        #pragma unroll
        for (int i = 0; i < 4; ++i) {
            const int j = w*4 + i;
            const int d = j*8 + (lane >> 3);
            const int u = (lane & 7) ^ (d & 7);
            gl_lds16(Vh + (size_t)d*SEQ + kt*64 + u*8, &Vb[buf][j*512]);
        }
    };

    stage(0, 0);

    for (int kt = 0; kt < SEQ/64; ++kt) {
        __syncthreads();                       // buf[kt&1] ready; prev reads of buf[(kt+1)&1] done
        if (kt + 1 < SEQ/64) stage((kt+1)&1, kt+1);
        const unsigned short* Kc = &Kb[kt&1][0];
        const unsigned short* Vc = &Vb[kt&1][0];

        #pragma unroll
        for (int s = 0; s < 2; ++s) {          // two 32-key MFMA steps
            // S^T = K·Q^T (A=K frags from swizzled LDS, B=Qf regs)
            float16 sv;
            #pragma unroll
            for (int r = 0; r < 16; ++r) sv[r] = 0.f;
            #pragma unroll
            for (int ch = 0; ch < 8; ++ch) {
                const int r = s*32 + l31;
                const int p = (2*ch + q5) ^ (l31 & 7);
                short8 kf = *(const short8*)&Kc[r*128 + p*8];
                sv = __builtin_amdgcn_mfma_f32_32x32x16_bf16(kf, Qf[ch], sv, 0, 0, 0);
            }
            // max-free softmax: p = exp2(s') == exp(s*SCALE); pack bf16 pairs
            unsigned pk[8];
            #pragma unroll
            for (int rp = 0; rp < 8; ++rp) {
                float p0 = exp2f(sv[2*rp]);
                float p1 = exp2f(sv[2*rp+1]);
                lsum += p0 + p1;
                pk[rp] = pack_bf16(p0, p1);
            }
            // P^T -> B-operand frags via 4 packed half-wave exchanges
            unsigned e0 = __shfl_xor(q5 ? pk[0] : pk[2], 32, 64);
            unsigned e1 = __shfl_xor(q5 ? pk[1] : pk[3], 32, 64);
            unsigned e2 = __shfl_xor(q5 ? pk[4] : pk[6], 32, 64);
            unsigned e3 = __shfl_xor(q5 ? pk[5] : pk[7], 32, 64);
            FR c0, c1;
            if (q5 == 0) {
                c0.u[0]=pk[0]; c0.u[1]=pk[1]; c0.u[2]=e0;    c0.u[3]=e1;
                c1.u[0]=pk[4]; c1.u[1]=pk[5]; c1.u[2]=e2;    c1.u[3]=e3;
            } else {
                c0.u[0]=e0;    c0.u[1]=e1;    c0.u[2]=pk[2]; c0.u[3]=pk[3];
                c1.u[0]=e2;    c1.u[1]=e3;    c1.u[2]=pk[6]; c1.u[3]=pk[7];
            }
            // O^T += V^T·P^T
            #pragma unroll
            for (int c = 0; c < 2; ++c) {
                short8 pf = c ? c1.s : c0.s;
                #pragma unroll
                for (int mt = 0; mt < 4; ++mt) {
                    const int d = mt*32 + l31;
                    const int u = s*4 + c*2 + q5;
                    const int p2 = u ^ (l31 & 7);
                    short8 vf = *(const short8*)&Vc[d*64 + p2*8];
                    o[mt] = __builtin_amdgcn_mfma_f32_32x32x16_bf16(vf, pf, o[mt], 0, 0, 0);
                }
            }
        }
    }

    const float l = lsum + __shfl_xor(lsum, 32, 64);
    const float inv = 1.f / l;
    float* orow = outg + ((size_t)head*SEQ + qblk*128 + w*32 + l31) * DIM;
    #pragma unroll
    for (int mt = 0; mt < 4; ++mt)
        #pragma unroll
        for (int rg = 0; rg < 4; ++rg) {
            const int d0 = mt*32 + rg*8 + q5*4;
            float4 ov;
            ov.x = o[mt][rg*4+0]*inv; ov.y = o[mt][rg*4+1]*inv;
            ov.z = o[mt][rg*4+2]*inv; ov.w = o[mt][rg*4+3]*inv;
            *(float4*)(orow + d0) = ov;
        }
}

// ---------------- blocked critical attention + MSE loss
__global__ __launch_bounds__(256) void crit_attn(
    const float* __restrict__ qg, const float* __restrict__ kg, const float* __restrict__ vg,
    const int* __restrict__ sidx, const float* __restrict__ keepg,
    const float* __restrict__ outg, float* __restrict__ lossp)
{
    __shared__ float Qs[32][132];
    __shared__ float Ks2[32][132];
    __shared__ float Vs[32][132];
    __shared__ float Sc[32][33];
    __shared__ float wsum[4];

    const int t  = threadIdx.x;
    const int nb = blockIdx.x;
    const int bh = nb >> 6;
    const int s0 = (nb & 63) * 32;
    const float kp = keepg[nb];
    const float* Qbase = qg + (size_t)bh*SEQ*DIM;
    const size_t rowbase = (size_t)nb * 32 * DIM;

    for (int i = t; i < 32*32; i += 256) {
        int row = i >> 5, c4 = (i & 31)*4;
        int qsrc = sidx[bh*SEQ + s0 + row];
        *(float4*)&Qs[row][c4] = *(const float4*)(Qbase + (size_t)qsrc*DIM + c4);
        float4 kv = *(const float4*)(kg + rowbase + (size_t)row*DIM + c4);
        kv.x*=kp; kv.y*=kp; kv.z*=kp; kv.w*=kp;
        *(float4*)&Ks2[row][c4] = kv;
        *(float4*)&Vs[row][c4] = *(const float4*)(vg + rowbase + (size_t)row*DIM + c4);
    }
    __syncthreads();

    const int r = t >> 3, u = t & 7;
    {
        float s[4] = {0.f,0.f,0.f,0.f};
        for (int d = 0; d < DIM; d += 4) {
            float4 a = *(const float4*)&Qs[r][d];
            #pragma unroll
            for (int j = 0; j < 4; ++j) {
                float4 bb = *(const float4*)&Ks2[u + 8*j][d];
                s[j]=fmaf(a.x,bb.x,s[j]); s[j]=fmaf(a.y,bb.y,s[j]);
                s[j]=fmaf(a.z,bb.z,s[j]); s[j]=fmaf(a.w,bb.w,s[j]);
            }
        }
        #pragma unroll
        for (int j = 0; j < 4; ++j) Sc[r][u+8*j] = s[j]*SCALE;
    }
    __syncthreads();
    if (t < 32) {
        float mx = -1e30f;
        for (int j = 0; j < 32; ++j) mx = fmaxf(mx, Sc[t][j]);
        float ls = 0.f;
        for (int j = 0; j < 32; ++j) { float p = __expf(Sc[t][j]-mx); Sc[t][j] = p; ls += p; }
        float inv = 1.f/ls;
        for (int j = 0; j < 32; ++j) Sc[t][j] *= inv;
    }
    __syncthreads();

    float sq = 0.f;
    {
        float acc[4][4];
        #pragma unroll
        for (int a2 = 0; a2 < 4; ++a2)
            #pragma unroll
            for (int b2 = 0; b2 < 4; ++b2) acc[a2][b2] = 0.f;
        for (int kk = 0; kk < 32; ++kk) {
            float p = Sc[r][kk];
            #pragma unroll
            for (int kq = 0; kq < 4; ++kq) {
                float4 vv = *(const float4*)&Vs[kk][kq*32 + u*4];
                acc[kq][0]=fmaf(p,vv.x,acc[kq][0]); acc[kq][1]=fmaf(p,vv.y,acc[kq][1]);
                acc[kq][2]=fmaf(p,vv.z,acc[kq][2]); acc[kq][3]=fmaf(p,vv.w,acc[kq][3]);
            }
        }
        const float* orow = outg + rowbase + (size_t)r*DIM;
        #pragma unroll
        for (int kq = 0; kq < 4; ++kq) {
            float4 oa = *(const float4*)(orow + kq*32 + u*4);
            float d0=acc[kq][0]-oa.x, d1=acc[kq][1]-oa.y, d2=acc[kq][2]-oa.z, d3=acc[kq][3]-oa.w;
            sq += d0*d0 + d1*d1 + d2*d2 + d3*d3;
        }
    }
    #pragma unroll
    for (int off = 32; off > 0; off >>= 1) sq += __shfl_down(sq, off, 64);
    if ((t & 63) == 0) wsum[t>>6] = sq;
    __syncthreads();
    if (t == 0) atomicAdd(lossp, (wsum[0]+wsum[1]+wsum[2]+wsum[3]) * (1.0f/8388608.0f));
}

extern "C" void kernel_launch(void* const* d_in, const int* in_sizes, int n_in,
                              void* d_out, int out_size, void* d_ws, size_t ws_size,
                              hipStream_t stream)
{
    const float* q    = (const float*)d_in[0];
    const float* k    = (const float*)d_in[1];
    const float* v    = (const float*)d_in[2];
    const float* proj = (const float*)d_in[3];
    float* out   = (float*)d_out;
    float* lossp = out + (out_size - 1);

    int* qh   = (int*)d_ws;
    int* kh   = qh + NROWS;
    int* sidx = kh + NROWS;
    int* qhs  = sidx + NROWS;
    float* keepg = (float*)(qhs + NROWS);
    unsigned short* kbf = (unsigned short*)(keepg + NBLK);   // 16 MB
    unsigned short* vtg = kbf + (size_t)NROWS*DIM;           // 16 MB

    hipMemsetAsync(lossp, 0, sizeof(float), stream);
    prep_kernel<<<NBH*32, 256, 0, stream>>>(k, v, kbf, vtg);
    hash_kernel<<<(2*NROWS)/4, 256, 0, stream>>>(q, k, proj, qh, kh);
    sort_kernel<<<NBH, 256, 0, stream>>>(qh, sidx, qhs);
    crit_kernel<<<NBLK/256, 256, 0, stream>>>(kh, qhs, keepg);
    dense_attn_mfma<<<512, 256, 0, stream>>>(kbf, vtg, q, out);
    crit_attn<<<NBLK, 256, 0, stream>>>(q, k, v, sidx, keepg, out, lossp);
}

// Round 4
// 357.981 us; speedup vs baseline: 4.4414x; 1.3177x over previous
//
#include <hip/hip_runtime.h>
#include <hip/hip_bf16.h>

#define SEQ 2048
#define DIM 128
#define NBH 32
#define NROWS (NBH*SEQ)      // 65536
#define NBLK (NROWS/32)      // 2048
#define SCALE 0.08838834764831845f  // 1/sqrt(128)
#define QSC (0.08838834764831845f * 1.4426950408889634f)  // SCALE*log2(e): exp2(s') == exp(s*SCALE)

typedef __attribute__((ext_vector_type(8))) short short8;
typedef __attribute__((ext_vector_type(16))) float float16;

__device__ __forceinline__ unsigned short f2bf(float x) {
    union { float f; unsigned u; } v; v.f = x;
    unsigned r = v.u + 0x7fffu + ((v.u >> 16) & 1u);   // RNE
    return (unsigned short)(r >> 16);
}
__device__ __forceinline__ unsigned pack_bf16(float a, float b) {
    float2 f; f.x = a; f.y = b;
    __hip_bfloat162 h = __float22bfloat162_rn(f);
    union { __hip_bfloat162 h2; unsigned u; } cv; cv.h2 = h; return cv.u;
}
__device__ __forceinline__ void gl_lds16(const void* g, void* l) {
    __builtin_amdgcn_global_load_lds((const __attribute__((address_space(1))) unsigned int*)g,
                                     (__attribute__((address_space(3))) unsigned int*)l, 16, 0, 0);
}

// ---------------- LSH hash: PERM[code] == code ^ (code>>1)
__global__ void hash_kernel(const float* __restrict__ qg, const float* __restrict__ kg,
                            const float* __restrict__ proj,
                            int* __restrict__ qh, int* __restrict__ kh)
{
    int gw   = (int)((blockIdx.x * blockDim.x + threadIdx.x) >> 6);
    int lane = threadIdx.x & 63;
    const float* src; int* dst; int row;
    if (gw < NROWS) { src = qg; dst = qh; row = gw; }
    else            { src = kg; dst = kh; row = gw - NROWS; }
    const float* x = src + (size_t)row * DIM;
    float a0=0.f,a1=0.f,a2=0.f,a3=0.f,a4=0.f,a5=0.f,a6=0.f;
    #pragma unroll
    for (int h = 0; h < 2; ++h) {
        int d = lane + 64*h;
        float xv = x[d];
        const float* p = proj + d*7;
        a0 = fmaf(xv, p[0], a0); a1 = fmaf(xv, p[1], a1);
        a2 = fmaf(xv, p[2], a2); a3 = fmaf(xv, p[3], a3);
        a4 = fmaf(xv, p[4], a4); a5 = fmaf(xv, p[5], a5);
        a6 = fmaf(xv, p[6], a6);
    }
    #pragma unroll
    for (int off = 32; off > 0; off >>= 1) {
        a0 += __shfl_xor(a0, off, 64); a1 += __shfl_xor(a1, off, 64);
        a2 += __shfl_xor(a2, off, 64); a3 += __shfl_xor(a3, off, 64);
        a4 += __shfl_xor(a4, off, 64); a5 += __shfl_xor(a5, off, 64);
        a6 += __shfl_xor(a6, off, 64);
    }
    if (lane == 0) {
        int code = 0;
        if (a0 > 0.f) code |= 1;  if (a1 > 0.f) code |= 2;
        if (a2 > 0.f) code |= 4;  if (a3 > 0.f) code |= 8;
        if (a4 > 0.f) code |= 16; if (a5 > 0.f) code |= 32;
        if (a6 > 0.f) code |= 64;
        dst[row] = code ^ (code >> 1);
    }
}

// ---------------- parallel stable counting sort per (b,h)
// Thread t owns elements [8t, 8t+8). rank = bucket_start[v] + (#v in threads<t) + (#v earlier in-thread).
__global__ __launch_bounds__(256) void sort_kernel(const int* __restrict__ qh,
                                                   int* __restrict__ sidx, int* __restrict__ qhs)
{
    __shared__ unsigned short cnt[128][257];   // [bucket][thread]; scanned in place; [256]=total
    __shared__ int startv[128];
    const int bh = blockIdx.x;
    const int t  = threadIdx.x;
    const int base = bh*SEQ;

    for (int i = t; i < 128*257; i += 256) ((unsigned short*)cnt)[i] = 0;
    __syncthreads();

    int hv[8];
    {
        int4 a = *(const int4*)(qh + base + t*8);
        int4 b = *(const int4*)(qh + base + t*8 + 4);
        hv[0]=a.x; hv[1]=a.y; hv[2]=a.z; hv[3]=a.w;
        hv[4]=b.x; hv[5]=b.y; hv[6]=b.z; hv[7]=b.w;
    }
    #pragma unroll
    for (int i = 0; i < 8; ++i) cnt[hv[i]][t]++;      // column t private to thread t
    __syncthreads();

    if (t < 128) {            // exclusive prefix over threads, bucket t
        unsigned s = 0;
        for (int j = 0; j < 256; ++j) { unsigned c = cnt[t][j]; cnt[t][j] = (unsigned short)s; s += c; }
        cnt[t][256] = (unsigned short)s;
    }
    __syncthreads();
    if (t == 0) {             // exclusive scan of bucket totals
        int s = 0;
        for (int v = 0; v < 128; ++v) { startv[v] = s; s += cnt[v][256]; }
    }
    __syncthreads();

    #pragma unroll
    for (int i = 0; i < 8; ++i) {
        const int v = hv[i];
        int prior = 0;
        #pragma unroll
        for (int j = 0; j < 8; ++j) if (j < i && hv[j] == v) ++prior;
        const int rank = startv[v] + (int)cnt[v][t] + prior;
        sidx[base + rank] = t*8 + i;
        qhs[base + rank]  = v;
    }
}

// ---------------- per-32-block criticality -> keep flag
__global__ void crit_kernel(const int* __restrict__ kh, const int* __restrict__ qhs,
                            float* __restrict__ keepg)
{
    int nb = blockIdx.x * blockDim.x + threadIdx.x;
    if (nb >= NBLK) return;
    int c = 0;
    #pragma unroll
    for (int i = 0; i < 32; ++i) c += (kh[nb*32+i] == qhs[nb*32+i]) ? 1 : 0;
    keepg[nb] = (c == 0) ? 1.0f : 0.0f;
}

// ---------------- prep: K -> bf16 row-major; V -> bf16 transposed [h][d][key]
__global__ __launch_bounds__(256) void prep_kernel(const float* __restrict__ kg,
                                                   const float* __restrict__ vg,
                                                   unsigned short* __restrict__ kbf,
                                                   unsigned short* __restrict__ vtg)
{
    __shared__ unsigned short T[128][72];
    const int t  = threadIdx.x;
    const int h  = blockIdx.x >> 5;
    const int sl = blockIdx.x & 31;
    const size_t base = ((size_t)h*SEQ + sl*64) * DIM;

    #pragma unroll
    for (int i = 0; i < 8; ++i) {
        const float4 f = *(const float4*)(kg + base + ((size_t)i*256 + t)*4);
        uint2 pk; pk.x = pack_bf16(f.x, f.y); pk.y = pack_bf16(f.z, f.w);
        *(uint2*)(kbf + base + ((size_t)i*256 + t)*4) = pk;
    }

    const int kk = t & 63, seg = t >> 6;
    #pragma unroll
    for (int i = 0; i < 8; ++i) {
        float4 f = *(const float4*)(vg + base + (size_t)kk*DIM + seg*32 + i*4);
        T[seg*32 + i*4 + 0][kk] = f2bf(f.x);
        T[seg*32 + i*4 + 1][kk] = f2bf(f.y);
        T[seg*32 + i*4 + 2][kk] = f2bf(f.z);
        T[seg*32 + i*4 + 3][kk] = f2bf(f.w);
    }
    __syncthreads();
    const int r = t >> 1, hf = t & 1;
    unsigned short* dst = vtg + ((size_t)h*DIM + r)*SEQ + sl*64 + hf*32;
    #pragma unroll
    for (int i = 0; i < 4; ++i)
        *(short8*)(dst + i*8) = *(const short8*)&T[r][hf*32 + i*8];
}

// ---------------- dense flash attention: bf16 MFMA, max-free softmax, async staging,
// double-buffered 64-key macro-tiles, XOR-swizzled LDS.
__global__ __launch_bounds__(256, 2) void dense_attn_mfma(
    const unsigned short* __restrict__ kbf, const unsigned short* __restrict__ vtg,
    const float* __restrict__ qg, float* __restrict__ outg)
{
    __shared__ __align__(16) unsigned short Kb[2][64*128];
    __shared__ __align__(16) unsigned short Vb[2][128*64];

    const int t    = threadIdx.x;
    const int lane = t & 63;
    const int w    = t >> 6;
    const int q5   = lane >> 5;
    const int l31  = lane & 31;

    const int b    = blockIdx.x;
    const int slot = b >> 3;
    const int head = (b & 7) * 4 + (slot >> 4);
    const int qblk = slot & 15;

    const float* Qg = qg + ((size_t)head*SEQ + qblk*128 + w*32) * DIM;
    const unsigned short* Kh = kbf + (size_t)head*SEQ*DIM;
    const unsigned short* Vh = vtg + (size_t)head*DIM*SEQ;

    union FR { unsigned u[4]; short8 s; };
    short8 Qf[8];
    #pragma unroll
    for (int ch = 0; ch < 8; ++ch) {
        const float* p = Qg + (size_t)l31*DIM + ch*16 + q5*8;
        float4 f0 = *(const float4*)p;
        float4 f1 = *(const float4*)(p + 4);
        FR fr;
        fr.u[0] = pack_bf16(f0.x*QSC, f0.y*QSC);
        fr.u[1] = pack_bf16(f0.z*QSC, f0.w*QSC);
        fr.u[2] = pack_bf16(f1.x*QSC, f1.y*QSC);
        fr.u[3] = pack_bf16(f1.z*QSC, f1.w*QSC);
        Qf[ch] = fr.s;
    }

    float16 o[4];
    #pragma unroll
    for (int mt = 0; mt < 4; ++mt)
        #pragma unroll
        for (int r = 0; r < 16; ++r) o[mt][r] = 0.f;
    float lsum = 0.f;

    auto stage = [&](int buf, int kt) {
        #pragma unroll
        for (int i = 0; i < 4; ++i) {
            const int j = w*4 + i;
            const int r = j*4 + (lane >> 4);
            const int u = (lane & 15) ^ (r & 7);
            gl_lds16(Kh + ((size_t)(kt*64 + r))*DIM + u*8, &Kb[buf][j*512]);
        }
        #pragma unroll
        for (int i = 0; i < 4; ++i) {
            const int j = w*4 + i;
            const int d = j*8 + (lane >> 3);
            const int u = (lane & 7) ^ (d & 7);
            gl_lds16(Vh + (size_t)d*SEQ + kt*64 + u*8, &Vb[buf][j*512]);
        }
    };

    stage(0, 0);

    for (int kt = 0; kt < SEQ/64; ++kt) {
        __syncthreads();
        if (kt + 1 < SEQ/64) stage((kt+1)&1, kt+1);
        const unsigned short* Kc = &Kb[kt&1][0];
        const unsigned short* Vc = &Vb[kt&1][0];

        #pragma unroll
        for (int s = 0; s < 2; ++s) {
            float16 sv;
            #pragma unroll
            for (int r = 0; r < 16; ++r) sv[r] = 0.f;
            #pragma unroll
            for (int ch = 0; ch < 8; ++ch) {
                const int r = s*32 + l31;
                const int p = (2*ch + q5) ^ (l31 & 7);
                short8 kf = *(const short8*)&Kc[r*128 + p*8];
                sv = __builtin_amdgcn_mfma_f32_32x32x16_bf16(kf, Qf[ch], sv, 0, 0, 0);
            }
            unsigned pk[8];
            #pragma unroll
            for (int rp = 0; rp < 8; ++rp) {
                float p0 = exp2f(sv[2*rp]);
                float p1 = exp2f(sv[2*rp+1]);
                lsum += p0 + p1;
                pk[rp] = pack_bf16(p0, p1);
            }
            unsigned e0 = __shfl_xor(q5 ? pk[0] : pk[2], 32, 64);
            unsigned e1 = __shfl_xor(q5 ? pk[1] : pk[3], 32, 64);
            unsigned e2 = __shfl_xor(q5 ? pk[4] : pk[6], 32, 64);
            unsigned e3 = __shfl_xor(q5 ? pk[5] : pk[7], 32, 64);
            FR c0, c1;
            if (q5 == 0) {
                c0.u[0]=pk[0]; c0.u[1]=pk[1]; c0.u[2]=e0;    c0.u[3]=e1;
                c1.u[0]=pk[4]; c1.u[1]=pk[5]; c1.u[2]=e2;    c1.u[3]=e3;
            } else {
                c0.u[0]=e0;    c0.u[1]=e1;    c0.u[2]=pk[2]; c0.u[3]=pk[3];
                c1.u[0]=e2;    c1.u[1]=e3;    c1.u[2]=pk[6]; c1.u[3]=pk[7];
            }
            #pragma unroll
            for (int c = 0; c < 2; ++c) {
                short8 pf = c ? c1.s : c0.s;
                #pragma unroll
                for (int mt = 0; mt < 4; ++mt) {
                    const int d = mt*32 + l31;
                    const int u = s*4 + c*2 + q5;
                    const int p2 = u ^ (l31 & 7);
                    short8 vf = *(const short8*)&Vc[d*64 + p2*8];
                    o[mt] = __builtin_amdgcn_mfma_f32_32x32x16_bf16(vf, pf, o[mt], 0, 0, 0);
                }
            }
        }
    }

    const float l = lsum + __shfl_xor(lsum, 32, 64);
    const float inv = 1.f / l;
    float* orow = outg + ((size_t)head*SEQ + qblk*128 + w*32 + l31) * DIM;
    #pragma unroll
    for (int mt = 0; mt < 4; ++mt)
        #pragma unroll
        for (int rg = 0; rg < 4; ++rg) {
            const int d0 = mt*32 + rg*8 + q5*4;
            float4 ov;
            ov.x = o[mt][rg*4+0]*inv; ov.y = o[mt][rg*4+1]*inv;
            ov.z = o[mt][rg*4+2]*inv; ov.w = o[mt][rg*4+3]*inv;
            *(float4*)(orow + d0) = ov;
        }
}

// ---------------- blocked critical attention + MSE loss
__global__ __launch_bounds__(256) void crit_attn(
    const float* __restrict__ qg, const float* __restrict__ kg, const float* __restrict__ vg,
    const int* __restrict__ sidx, const float* __restrict__ keepg,
    const float* __restrict__ outg, float* __restrict__ lossp)
{
    __shared__ float Qs[32][132];
    __shared__ float Ks2[32][132];
    __shared__ float Vs[32][132];
    __shared__ float Sc[32][33];
    __shared__ float wsum[4];

    const int t  = threadIdx.x;
    const int nb = blockIdx.x;
    const int bh = nb >> 6;
    const int s0 = (nb & 63) * 32;
    const float kp = keepg[nb];
    const float* Qbase = qg + (size_t)bh*SEQ*DIM;
    const size_t rowbase = (size_t)nb * 32 * DIM;

    for (int i = t; i < 32*32; i += 256) {
        int row = i >> 5, c4 = (i & 31)*4;
        int qsrc = sidx[bh*SEQ + s0 + row];
        *(float4*)&Qs[row][c4] = *(const float4*)(Qbase + (size_t)qsrc*DIM + c4);
        float4 kv = *(const float4*)(kg + rowbase + (size_t)row*DIM + c4);
        kv.x*=kp; kv.y*=kp; kv.z*=kp; kv.w*=kp;
        *(float4*)&Ks2[row][c4] = kv;
        *(float4*)&Vs[row][c4] = *(const float4*)(vg + rowbase + (size_t)row*DIM + c4);
    }
    __syncthreads();

    const int r = t >> 3, u = t & 7;
    {
        float s[4] = {0.f,0.f,0.f,0.f};
        for (int d = 0; d < DIM; d += 4) {
            float4 a = *(const float4*)&Qs[r][d];
            #pragma unroll
            for (int j = 0; j < 4; ++j) {
                float4 bb = *(const float4*)&Ks2[u + 8*j][d];
                s[j]=fmaf(a.x,bb.x,s[j]); s[j]=fmaf(a.y,bb.y,s[j]);
                s[j]=fmaf(a.z,bb.z,s[j]); s[j]=fmaf(a.w,bb.w,s[j]);
            }
        }
        #pragma unroll
        for (int j = 0; j < 4; ++j) Sc[r][u+8*j] = s[j]*SCALE;
    }
    __syncthreads();
    if (t < 32) {
        float mx = -1e30f;
        for (int j = 0; j < 32; ++j) mx = fmaxf(mx, Sc[t][j]);
        float ls = 0.f;
        for (int j = 0; j < 32; ++j) { float p = __expf(Sc[t][j]-mx); Sc[t][j] = p; ls += p; }
        float inv = 1.f/ls;
        for (int j = 0; j < 32; ++j) Sc[t][j] *= inv;
    }
    __syncthreads();

    float sq = 0.f;
    {
        float acc[4][4];
        #pragma unroll
        for (int a2 = 0; a2 < 4; ++a2)
            #pragma unroll
            for (int b2 = 0; b2 < 4; ++b2) acc[a2][b2] = 0.f;
        for (int kk = 0; kk < 32; ++kk) {
            float p = Sc[r][kk];
            #pragma unroll
            for (int kq = 0; kq < 4; ++kq) {
                float4 vv = *(const float4*)&Vs[kk][kq*32 + u*4];
                acc[kq][0]=fmaf(p,vv.x,acc[kq][0]); acc[kq][1]=fmaf(p,vv.y,acc[kq][1]);
                acc[kq][2]=fmaf(p,vv.z,acc[kq][2]); acc[kq][3]=fmaf(p,vv.w,acc[kq][3]);
            }
        }
        const float* orow = outg + rowbase + (size_t)r*DIM;
        #pragma unroll
        for (int kq = 0; kq < 4; ++kq) {
            float4 oa = *(const float4*)(orow + kq*32 + u*4);
            float d0=acc[kq][0]-oa.x, d1=acc[kq][1]-oa.y, d2=acc[kq][2]-oa.z, d3=acc[kq][3]-oa.w;
            sq += d0*d0 + d1*d1 + d2*d2 + d3*d3;
        }
    }
    #pragma unroll
    for (int off = 32; off > 0; off >>= 1) sq += __shfl_down(sq, off, 64);
    if ((t & 63) == 0) wsum[t>>6] = sq;
    __syncthreads();
    if (t == 0) atomicAdd(lossp, (wsum[0]+wsum[1]+wsum[2]+wsum[3]) * (1.0f/8388608.0f));
}

extern "C" void kernel_launch(void* const* d_in, const int* in_sizes, int n_in,
                              void* d_out, int out_size, void* d_ws, size_t ws_size,
                              hipStream_t stream)
{
    const float* q    = (const float*)d_in[0];
    const float* k    = (const float*)d_in[1];
    const float* v    = (const float*)d_in[2];
    const float* proj = (const float*)d_in[3];
    float* out   = (float*)d_out;
    float* lossp = out + (out_size - 1);

    int* qh   = (int*)d_ws;
    int* kh   = qh + NROWS;
    int* sidx = kh + NROWS;
    int* qhs  = sidx + NROWS;
    float* keepg = (float*)(qhs + NROWS);
    unsigned short* kbf = (unsigned short*)(keepg + NBLK);   // 16 MB
    unsigned short* vtg = kbf + (size_t)NROWS*DIM;           // 16 MB

    hipMemsetAsync(lossp, 0, sizeof(float), stream);
    prep_kernel<<<NBH*32, 256, 0, stream>>>(k, v, kbf, vtg);
    hash_kernel<<<(2*NROWS)/4, 256, 0, stream>>>(q, k, proj, qh, kh);
    sort_kernel<<<NBH, 256, 0, stream>>>(qh, sidx, qhs);
    crit_kernel<<<NBLK/256, 256, 0, stream>>>(kh, qhs, keepg);
    dense_attn_mfma<<<512, 256, 0, stream>>>(kbf, vtg, q, out);
    crit_attn<<<NBLK, 256, 0, stream>>>(q, k, v, sidx, keepg, out, lossp);
}